// Round 11
// baseline (141.172 us; speedup 1.0000x reference)
//
#include <hip/hip_runtime.h>

// Rec1_43748536877661 — diagonal SSM block, MI355X gfx950.
// B=2,S=2048,D=128,N=2048. fp32 in/out, bf16 MFMA compute (tol 2.14e-2).
// R11: R9 skeleton, chain depth halved. grid(8,64): 32 t-tiles per block
// (8 per wave), serial tagged-atomic lookback now only 3 hops per batch.
// outproj flattened: 2 d-tiles per wave, full K, no LDS reduce.
//  1. prep      pack W_B/dt/C,W_out fragment-linear bf16; Aval=-exp(A_log)
//  2. projscan  grid(8,64): GEMM+scan local, tagged relaxed agent-scope
//               lookback (poison 0xAA != tag 1 => no Sbuf clear), in-register
//               fixup -> y (bf16 A-frag packed)
//  3. outproj   y @ W_out^T + b_out -> fp32 out
// Deadlock safety: non-head blocks (bx&3 != 0) wait only on bx-1 of the SAME
// by row; full grid (512 blocks) co-resident at >= 2 blocks/CU.

#define BB 2
#define SS 2048
#define DDIM 128
#define NDIM 2048
#define TT (BB*SS)        // 4096 tokens
#define NTILE (TT/16)     // 256 t-tiles

typedef short short8 __attribute__((ext_vector_type(8)));
typedef float floatx4 __attribute__((ext_vector_type(4)));

__device__ __forceinline__ unsigned short f2b(float f){
  unsigned u = __float_as_uint(f);
  u += 0x7FFFu + ((u >> 16) & 1u);
  return (unsigned short)(u >> 16);
}
__device__ __forceinline__ float softplus_f(float v){
  return v > 15.f ? v : __logf(1.f + __expf(v));
}
__device__ __forceinline__ short8 cvt8(floatx4 u, floatx4 v){
  short8 t;
  t[0]=(short)f2b(u[0]); t[1]=(short)f2b(u[1]); t[2]=(short)f2b(u[2]); t[3]=(short)f2b(u[3]);
  t[4]=(short)f2b(v[0]); t[5]=(short)f2b(v[1]); t[6]=(short)f2b(v[2]); t[7]=(short)f2b(v[3]);
  return t;
}
__device__ __forceinline__ void pack8(const float* __restrict__ s,
                                      unsigned short* __restrict__ d){
  floatx4 v0 = *(const floatx4*)s;
  floatx4 v1 = *(const floatx4*)(s + 4);
  *(short8*)d = cvt8(v0, v1);
}
#define TAGW(x) ((1ull << 32) | (unsigned long long)__float_as_uint(x))

// ---------------- 1. prep: weights + Aval only ----------------
__global__ void prep_kernel(const float* __restrict__ W_B,
                            const float* __restrict__ W_C,
                            const float* __restrict__ W_dt,
                            const float* __restrict__ A_log,
                            const float* __restrict__ W_out,
                            unsigned short* __restrict__ Wp3,
                            unsigned short* __restrict__ Wop,
                            float* __restrict__ Aval){
  const int gid = blockIdx.x * blockDim.x + threadIdx.x;   // 0..98303
  if (gid < 2048) Aval[gid] = -__expf(A_log[gid]);
  if (gid < 98304){                               // W_B/W_dt/W_C: 128 n-tiles each
    int mat = gid >> 15, g = gid & 32767;
    const float* W = (mat == 0) ? W_B : (mat == 1 ? W_dt : W_C);
    int tile = g >> 8, kk = (g >> 6) & 3, lane = g & 63;
    int q = lane >> 4, m = lane & 15;
    pack8(W + (size_t)(tile*16 + m)*DDIM + kk*32 + q*8,
          Wp3 + (size_t)mat*262144 + (size_t)g*8);
  }
  if (gid < 32768){                               // W_out: 8 d-tiles, K=2048
    int g = gid, tile = g >> 12, kk = (g >> 6) & 63, lane = g & 63;
    int q = lane >> 4, m = lane & 15;
    pack8(W_out + (size_t)(tile*16 + m)*NDIM + kk*32 + q*8, Wop + (size_t)g*8);
  }
}

// ---------------- 2. projscan, chain depth 4 ----------------
// grid (8, 64), block 256. bx = t-chunk (32 tiles = 512 t), by = 32-n slice.
// Wave wv handles tiles bx*32 + wv*8 .. +8 sequentially.
// Batch: bx 0..3 = b0, 4..7 = b1; bx&3==0 starts at h=0.
__global__ __launch_bounds__(256, 2) void projscan_kernel(
    const float* __restrict__ xG,
    const unsigned short* __restrict__ Wp3,
    const float* __restrict__ b_B,
    const float* __restrict__ b_dt,
    const float* __restrict__ b_C,
    const float* __restrict__ Aval,
    unsigned long long* __restrict__ Sbuf,   // [64*8][32] tagged inclusive states
    unsigned short* __restrict__ ybp){
  __shared__ unsigned short sW[3*4096];      // 24 KB packed weights (this n-slice)
  __shared__ unsigned short sYT[4][16*40];   // per-wave transpose tile
  __shared__ float sPw[4][32], sHw[4][32];   // per-wave chain totals
  __shared__ float sIw[4][32];               // per-wave init states
  const int tid  = threadIdx.x;
  const int lane = tid & 63;
  const int wv   = tid >> 6;
  const int m    = lane & 15;
  const int q    = lane >> 4;
  const int bx   = blockIdx.x;
  const int by   = blockIdx.y;
  const int n0   = by*32;
  const int cid  = by*8 + bx;

  // stage packed weights: 3 mats x 2 n-tiles x 2048 ushort
  for (int i = tid; i < 1536; i += 256){
    int mat = i >> 9, rem = i & 511;
    *(short8*)(sW + mat*4096 + rem*8) =
        *(const short8*)(Wp3 + (size_t)mat*262144 + (size_t)by*4096 + rem*8);
  }
  __syncthreads();

  // per-nt biases (n = n0 + nt*16 + m)
  float bBv[2], bDv[2], bCv[2], Avv[2];
#pragma unroll
  for (int nt = 0; nt < 2; ++nt){
    const int n = n0 + nt*16 + m;
    bBv[nt] = b_B[n]; bDv[nt] = b_dt[n]; bCv[nt] = b_C[n]; Avv[nt] = Aval[n];
  }

  // ---- Phase A: 8 sequential tiles, local scan (init 0), y/coef packed regs
  unsigned ypk[8][2][2], cpk[8][2][2];
  float pe_t[8][2], he_t[8][2];
  float pa_run[2] = {1.f, 1.f}, ha_run[2] = {0.f, 0.f};

#pragma unroll
  for (int i = 0; i < 8; ++i){
    const int tile = bx*32 + wv*8 + i;
    // x fragments direct from fp32: A[m][kk*32 + q*8 + j]
    short8 xf[4];
    const float* xr = xG + (size_t)(tile*16 + m)*DDIM + q*8;
#pragma unroll
    for (int kk = 0; kk < 4; ++kk){
      floatx4 u = *(const floatx4*)(xr + kk*32);
      floatx4 v = *(const floatx4*)(xr + kk*32 + 4);
      xf[kk] = cvt8(u, v);
    }

    floatx4 acc[3][2];
#pragma unroll
    for (int mat = 0; mat < 3; ++mat)
#pragma unroll
      for (int nt = 0; nt < 2; ++nt)
        acc[mat][nt] = (floatx4){0.f,0.f,0.f,0.f};
#pragma unroll
    for (int nt = 0; nt < 2; ++nt)
#pragma unroll
      for (int kk = 0; kk < 4; ++kk){
        short8 wB = *(const short8*)(sW +         nt*2048 + kk*512 + lane*8);
        short8 wD = *(const short8*)(sW + 4096 +  nt*2048 + kk*512 + lane*8);
        short8 wC = *(const short8*)(sW + 8192 +  nt*2048 + kk*512 + lane*8);
        acc[0][nt] = __builtin_amdgcn_mfma_f32_16x16x32_bf16(xf[kk], wB, acc[0][nt], 0, 0, 0);
        acc[1][nt] = __builtin_amdgcn_mfma_f32_16x16x32_bf16(xf[kk], wD, acc[1][nt], 0, 0, 0);
        acc[2][nt] = __builtin_amdgcn_mfma_f32_16x16x32_bf16(xf[kk], wC, acc[2][nt], 0, 0, 0);
      }

#pragma unroll
    for (int nt = 0; nt < 2; ++nt){
      float Ar[4], Br[4], Cc[4];
#pragma unroll
      for (int r = 0; r < 4; ++r){
        float dtv = softplus_f(acc[1][nt][r] + bDv[nt]);
        Ar[r] = __expf(dtv * Avv[nt]);
        Br[r] = dtv * (acc[0][nt][r] + bBv[nt]);
        Cc[r] = acc[2][nt][r] + bCv[nt];
      }
      float P = Ar[0], H = Br[0];
#pragma unroll
      for (int r = 1; r < 4; ++r){ H = Ar[r]*H + Br[r]; P *= Ar[r]; }
      float pp = __shfl(P, (lane - 16) & 63, 64);
      float hh = __shfl(H, (lane - 16) & 63, 64);
      if (q >= 1){ H = P*hh + H; P *= pp; }
      pp = __shfl(P, (lane - 32) & 63, 64);
      hh = __shfl(H, (lane - 32) & 63, 64);
      if (q >= 2){ H = P*hh + H; P *= pp; }
      float pe = __shfl(P, (lane - 16) & 63, 64);
      float he = __shfl(H, (lane - 16) & 63, 64);
      if (q == 0){ pe = 1.f; he = 0.f; }
      float pb = __shfl(P, m + 48, 64);
      float hb = __shfl(H, m + 48, 64);

      float h = he, pa = pe;
      unsigned short yr[4], cr[4];
#pragma unroll
      for (int r = 0; r < 4; ++r){
        h = Ar[r]*h + Br[r];
        pa *= Ar[r];
        yr[r] = f2b(Cc[r]*h);
        cr[r] = f2b(Cc[r]*pa);
      }
      ypk[i][nt][0] = (unsigned)yr[0] | ((unsigned)yr[1] << 16);
      ypk[i][nt][1] = (unsigned)yr[2] | ((unsigned)yr[3] << 16);
      cpk[i][nt][0] = (unsigned)cr[0] | ((unsigned)cr[1] << 16);
      cpk[i][nt][1] = (unsigned)cr[2] | ((unsigned)cr[3] << 16);

      pe_t[i][nt] = pa_run[nt];
      he_t[i][nt] = ha_run[nt];
      ha_run[nt] = pb*ha_run[nt] + hb;
      pa_run[nt] *= pb;
    }
  }
  if (q == 0){
#pragma unroll
    for (int nt = 0; nt < 2; ++nt){
      sPw[wv][nt*16 + m] = pa_run[nt];
      sHw[wv][nt*16 + m] = ha_run[nt];
    }
  }
  __syncthreads();

  // ---- Phase B: serial tagged-atomic lookback (threads 0..31, n = n0 + tid)
  if (tid < 32){
    float Pw[4], Hw[4];
#pragma unroll
    for (int w2 = 0; w2 < 4; ++w2){ Pw[w2] = sPw[w2][tid]; Hw[w2] = sHw[w2][tid]; }
    float Sj = 0.f;
    if (bx & 3){
      const unsigned long long* src = Sbuf + (size_t)(cid - 1)*32 + tid;
      unsigned long long v;
      for (;;){
        v = __hip_atomic_load(src, __ATOMIC_RELAXED, __HIP_MEMORY_SCOPE_AGENT);
        if ((unsigned)(v >> 32) == 1u) break;
        __builtin_amdgcn_s_sleep(1);
      }
      Sj = __uint_as_float((unsigned)v);
    }
    float s = Sj;
#pragma unroll
    for (int w2 = 0; w2 < 4; ++w2){
      sIw[w2][tid] = s;
      s = Pw[w2]*s + Hw[w2];
    }
    __hip_atomic_store(Sbuf + (size_t)cid*32 + tid, TAGW(s),
                       __ATOMIC_RELAXED, __HIP_MEMORY_SCOPE_AGENT);
  }
  __syncthreads();

  // ---- Phase C: fixup + transpose + store
  float iw[2];
#pragma unroll
  for (int nt = 0; nt < 2; ++nt) iw[nt] = sIw[wv][nt*16 + m];
#pragma unroll
  for (int i = 0; i < 8; ++i){
    const int tile = bx*32 + wv*8 + i;
#pragma unroll
    for (int nt = 0; nt < 2; ++nt){
      float it = pe_t[i][nt]*iw[nt] + he_t[i][nt];
#pragma unroll
      for (int j = 0; j < 2; ++j){
        unsigned yp = ypk[i][nt][j], cp = cpk[i][nt][j];
        float y0 = __uint_as_float(yp << 16);
        float y1 = __uint_as_float(yp & 0xffff0000u);
        float c0 = __uint_as_float(cp << 16);
        float c1 = __uint_as_float(cp & 0xffff0000u);
        sYT[wv][(q*4 + j*2 + 0)*40 + nt*16 + m] = f2b(y0 + c0*it);
        sYT[wv][(q*4 + j*2 + 1)*40 + nt*16 + m] = f2b(y1 + c1*it);
      }
    }
    short8 yv = *(const short8*)&sYT[wv][m*40 + q*8];
    *(short8*)(ybp + (size_t)tile*32768 + (size_t)by*512 + (size_t)lane*8) = yv;
  }
}

// ---------------- 3. output projection (direct, no LDS reduce) ----------------
// grid NTILE=256, block 256. Wave wv handles d-tiles wv*2, wv*2+1 over full K.
__global__ void outproj_kernel(const unsigned short* __restrict__ ybp,
                               const unsigned short* __restrict__ Wop,
                               const float* __restrict__ b_out,
                               float* __restrict__ out){
  const int tid  = threadIdx.x;
  const int lane = tid & 63;
  const int wv   = tid >> 6;
  const int m    = lane & 15;
  const int q    = lane >> 4;
  const int tile = blockIdx.x;
  const int dt0  = wv*2;

  floatx4 acc0 = {0.f,0.f,0.f,0.f}, acc1 = acc0;
  const unsigned short* aP = ybp + (size_t)tile*32768 + lane*8;
  const unsigned short* bP = Wop + (size_t)dt0*32768 + lane*8;
#pragma unroll 8
  for (int kk = 0; kk < 64; ++kk){
    short8 af = *(const short8*)(aP + (size_t)kk*512);
    short8 b0 = *(const short8*)(bP + (size_t)kk*512);
    short8 b1 = *(const short8*)(bP + 32768 + (size_t)kk*512);
    acc0 = __builtin_amdgcn_mfma_f32_16x16x32_bf16(af, b0, acc0, 0, 0, 0);
    acc1 = __builtin_amdgcn_mfma_f32_16x16x32_bf16(af, b1, acc1, 0, 0, 0);
  }
  const int d0 = dt0*16 + m;
  const float bo0 = b_out[d0], bo1 = b_out[d0 + 16];
#pragma unroll
  for (int r = 0; r < 4; ++r){
    const size_t row = (size_t)(tile*16 + q*4 + r)*DDIM;
    out[row + d0]      = acc0[r] + bo0;
    out[row + d0 + 16] = acc1[r] + bo1;
  }
}

extern "C" void kernel_launch(void* const* d_in, const int* in_sizes, int n_in,
                              void* d_out, int out_size, void* d_ws, size_t ws_size,
                              hipStream_t stream) {
  const float* x     = (const float*)d_in[0];
  const float* W_B   = (const float*)d_in[1];
  const float* b_B   = (const float*)d_in[2];
  const float* W_C   = (const float*)d_in[3];
  const float* b_C   = (const float*)d_in[4];
  const float* W_dt  = (const float*)d_in[5];
  const float* b_dt  = (const float*)d_in[6];
  const float* A_log = (const float*)d_in[7];
  const float* W_out = (const float*)d_in[8];
  const float* b_out = (const float*)d_in[9];
  float* out = (float*)d_out;

  char* w = (char*)d_ws;
  unsigned short*     Wp3  = (unsigned short*)    (w + 0x0000000);  // 1.5 MB
  unsigned short*     Wop  = (unsigned short*)    (w + 0x0180000);  // 0.5 MB
  float*              Aval = (float*)             (w + 0x0200000);  // 8 KB
  unsigned short*     ybp  = (unsigned short*)    (w + 0x0210000);  // 16 MB
  unsigned long long* Sbuf = (unsigned long long*)(w + 0x1210000);  // 128 KB
  // total ~18.2 MB. Sbuf NOT cleared: 0xAA poison tag != 1 reads "not ready".

  prep_kernel<<<384, 256, 0, stream>>>(
      W_B, W_C, W_dt, A_log, W_out, Wp3, Wop, Aval);

  projscan_kernel<<<dim3(8, 64), 256, 0, stream>>>(
      x, Wp3, b_B, b_dt, b_C, Aval, Sbuf, ybp);

  outproj_kernel<<<NTILE, 256, 0, stream>>>(ybp, Wop, b_out, out);
}

// Round 12
// 120.267 us; speedup vs baseline: 1.1738x; 1.1738x over previous
//
#include <hip/hip_runtime.h>

// Rec1_43748536877661 — diagonal SSM block, MI355X gfx950.
// B=2,S=2048,D=128,N=2048. fp32 in/out, bf16 MFMA compute (tol 2.14e-2).
// R12 = R9 optimum (chain depth 8, 4 tiles/wave, VGPR 88 no-spill, tagged
// relaxed agent-scope lookback) + R11's flattened outproj (2 d-tiles/wave,
// no LDS reduce). R11's depth-4 chain spilled (85MB scratch); reverted.
//  1. prep      pack x,W_B/dt/C,W_out fragment-linear bf16; Aval; zero Sbuf
//  2. projscan  grid(16,64): 16 t-tiles x 32 n per block; GEMM+scan local,
//               tagged-atomic lookback, in-register fixup -> y (bf16 A-frag)
//  3. outproj   y @ W_out^T + b_out -> fp32 out

#define BB 2
#define SS 2048
#define DDIM 128
#define NDIM 2048
#define TT (BB*SS)        // 4096 tokens
#define NTILE (TT/16)     // 256 t-tiles

typedef short short8 __attribute__((ext_vector_type(8)));
typedef float floatx4 __attribute__((ext_vector_type(4)));

__device__ __forceinline__ unsigned short f2b(float f){
  unsigned u = __float_as_uint(f);
  u += 0x7FFFu + ((u >> 16) & 1u);
  return (unsigned short)(u >> 16);
}
__device__ __forceinline__ float softplus_f(float v){
  return v > 15.f ? v : __logf(1.f + __expf(v));
}
__device__ __forceinline__ void pack8(const float* __restrict__ s,
                                      unsigned short* __restrict__ d){
  floatx4 v0 = *(const floatx4*)s;
  floatx4 v1 = *(const floatx4*)(s + 4);
  short8 r;
  r[0]=(short)f2b(v0[0]); r[1]=(short)f2b(v0[1]); r[2]=(short)f2b(v0[2]); r[3]=(short)f2b(v0[3]);
  r[4]=(short)f2b(v1[0]); r[5]=(short)f2b(v1[1]); r[6]=(short)f2b(v1[2]); r[7]=(short)f2b(v1[3]);
  *(short8*)d = r;
}

// ---------------- 1. prep ----------------
__global__ void prep_kernel(const float* __restrict__ x,
                            const float* __restrict__ W_B,
                            const float* __restrict__ W_C,
                            const float* __restrict__ W_dt,
                            const float* __restrict__ A_log,
                            const float* __restrict__ W_out,
                            unsigned short* __restrict__ xp,
                            unsigned short* __restrict__ Wp3,
                            unsigned short* __restrict__ Wop,
                            float* __restrict__ Aval,
                            unsigned long long* __restrict__ Sbuf){
  const int gid = blockIdx.x * blockDim.x + threadIdx.x;   // 0..98303
  if (gid < 32768) Sbuf[gid] = 0ull;              // clear tags (1024 x 32)
  if (gid < 2048) Aval[gid] = -__expf(A_log[gid]);
  if (gid < 65536){                               // x: 256 t-tiles, K=128
    int g = gid, tile = g >> 8, kk = (g >> 6) & 3, lane = g & 63;
    int q = lane >> 4, m = lane & 15;
    pack8(x + (size_t)(tile*16 + m)*DDIM + kk*32 + q*8, xp + (size_t)g*8);
  }
  if (gid < 98304){                               // W_B/W_dt/W_C: 128 n-tiles each
    int mat = gid >> 15, g = gid & 32767;
    const float* W = (mat == 0) ? W_B : (mat == 1 ? W_dt : W_C);
    int tile = g >> 8, kk = (g >> 6) & 3, lane = g & 63;
    int q = lane >> 4, m = lane & 15;
    pack8(W + (size_t)(tile*16 + m)*DDIM + kk*32 + q*8,
          Wp3 + (size_t)mat*262144 + (size_t)g*8);
  }
  if (gid < 32768){                               // W_out: 8 d-tiles, K=2048
    int g = gid, tile = g >> 12, kk = (g >> 6) & 63, lane = g & 63;
    int q = lane >> 4, m = lane & 15;
    pack8(W_out + (size_t)(tile*16 + m)*NDIM + kk*32 + q*8, Wop + (size_t)g*8);
  }
}

// ---------------- 2. projscan with tagged-atomic lookback ----------------
// grid (16, 64), block 256. bx = t-chunk (16 tiles), by = 32-n slice.
// Wave wv handles tiles bx*16 + wv*4 .. +4. bx%8==0 starts a batch (h=0).
__global__ __launch_bounds__(256, 2) void projscan_kernel(
    const unsigned short* __restrict__ xp,
    const unsigned short* __restrict__ Wp3,
    const float* __restrict__ b_B,
    const float* __restrict__ b_dt,
    const float* __restrict__ b_C,
    const float* __restrict__ Aval,
    unsigned long long* __restrict__ Sbuf,   // [64*16][32] tagged chain states
    unsigned short* __restrict__ ybp){
  __shared__ unsigned short sW[3*4096];      // 24 KB packed weights (this n-slice)
  __shared__ unsigned short sYT[4][16*40];   // per-wave transpose tile
  __shared__ float sPw[4][32], sHw[4][32];   // per-wave chain totals
  __shared__ float sIw[4][32];               // per-wave init states
  const int tid  = threadIdx.x;
  const int lane = tid & 63;
  const int wv   = tid >> 6;
  const int m    = lane & 15;
  const int q    = lane >> 4;
  const int bx   = blockIdx.x;
  const int by   = blockIdx.y;               // chain id
  const int n0   = by*32;

  // stage packed weights: 3 mats x 2 n-tiles x 2048 ushort
  for (int i = tid; i < 1536; i += 256){
    int mat = i >> 9, rem = i & 511;
    *(short8*)(sW + mat*4096 + rem*8) =
        *(const short8*)(Wp3 + (size_t)mat*262144 + (size_t)by*4096 + rem*8);
  }
  __syncthreads();

  // per-nt biases (n = n0 + nt*16 + m)
  float bBv[2], bDv[2], bCv[2], Avv[2];
#pragma unroll
  for (int nt = 0; nt < 2; ++nt){
    const int n = n0 + nt*16 + m;
    bBv[nt] = b_B[n]; bDv[nt] = b_dt[n]; bCv[nt] = b_C[n]; Avv[nt] = Aval[n];
  }

  // ---- Phase A: 4 sequential tiles, local scan (init 0), keep y/coef packed
  unsigned ypk[4][2][2], cpk[4][2][2];
  float pe_t[4][2], he_t[4][2];
  float pa_run[2] = {1.f, 1.f}, ha_run[2] = {0.f, 0.f};

#pragma unroll
  for (int i = 0; i < 4; ++i){
    const int tile = bx*16 + wv*4 + i;
    short8 xf[4];
#pragma unroll
    for (int kk = 0; kk < 4; ++kk)
      xf[kk] = *(const short8*)(xp + (size_t)tile*2048 + kk*512 + lane*8);

    floatx4 acc[3][2];
#pragma unroll
    for (int mat = 0; mat < 3; ++mat)
#pragma unroll
      for (int nt = 0; nt < 2; ++nt)
        acc[mat][nt] = (floatx4){0.f,0.f,0.f,0.f};
#pragma unroll
    for (int nt = 0; nt < 2; ++nt)
#pragma unroll
      for (int kk = 0; kk < 4; ++kk){
        short8 wB = *(const short8*)(sW +         nt*2048 + kk*512 + lane*8);
        short8 wD = *(const short8*)(sW + 4096 +  nt*2048 + kk*512 + lane*8);
        short8 wC = *(const short8*)(sW + 8192 +  nt*2048 + kk*512 + lane*8);
        acc[0][nt] = __builtin_amdgcn_mfma_f32_16x16x32_bf16(xf[kk], wB, acc[0][nt], 0, 0, 0);
        acc[1][nt] = __builtin_amdgcn_mfma_f32_16x16x32_bf16(xf[kk], wD, acc[1][nt], 0, 0, 0);
        acc[2][nt] = __builtin_amdgcn_mfma_f32_16x16x32_bf16(xf[kk], wC, acc[2][nt], 0, 0, 0);
      }

#pragma unroll
    for (int nt = 0; nt < 2; ++nt){
      float Ar[4], Br[4], Cc[4];
#pragma unroll
      for (int r = 0; r < 4; ++r){
        float dtv = softplus_f(acc[1][nt][r] + bDv[nt]);
        Ar[r] = __expf(dtv * Avv[nt]);
        Br[r] = dtv * (acc[0][nt][r] + bBv[nt]);
        Cc[r] = acc[2][nt][r] + bCv[nt];
      }
      // compose lane's 4-token segment
      float P = Ar[0], H = Br[0];
#pragma unroll
      for (int r = 1; r < 4; ++r){ H = Ar[r]*H + Br[r]; P *= Ar[r]; }
      // inclusive scan across q (2 steps)
      float pp = __shfl(P, (lane - 16) & 63, 64);
      float hh = __shfl(H, (lane - 16) & 63, 64);
      if (q >= 1){ H = P*hh + H; P *= pp; }
      pp = __shfl(P, (lane - 32) & 63, 64);
      hh = __shfl(H, (lane - 32) & 63, 64);
      if (q >= 2){ H = P*hh + H; P *= pp; }
      // exclusive prefix for this q
      float pe = __shfl(P, (lane - 16) & 63, 64);
      float he = __shfl(H, (lane - 16) & 63, 64);
      if (q == 0){ pe = 1.f; he = 0.f; }
      // tile totals broadcast (q==3 inclusive)
      float pb = __shfl(P, m + 48, 64);
      float hb = __shfl(H, m + 48, 64);

      float h = he, pa = pe;
      unsigned short yr[4], cr[4];
#pragma unroll
      for (int r = 0; r < 4; ++r){
        h = Ar[r]*h + Br[r];
        pa *= Ar[r];
        yr[r] = f2b(Cc[r]*h);
        cr[r] = f2b(Cc[r]*pa);
      }
      ypk[i][nt][0] = (unsigned)yr[0] | ((unsigned)yr[1] << 16);
      ypk[i][nt][1] = (unsigned)yr[2] | ((unsigned)yr[3] << 16);
      cpk[i][nt][0] = (unsigned)cr[0] | ((unsigned)cr[1] << 16);
      cpk[i][nt][1] = (unsigned)cr[2] | ((unsigned)cr[3] << 16);

      pe_t[i][nt] = pa_run[nt];
      he_t[i][nt] = ha_run[nt];
      ha_run[nt] = pb*ha_run[nt] + hb;
      pa_run[nt] *= pb;
    }
  }
  // publish wave totals per n (identical across q; q==0 writes)
  if (q == 0){
#pragma unroll
    for (int nt = 0; nt < 2; ++nt){
      sPw[wv][nt*16 + m] = pa_run[nt];
      sHw[wv][nt*16 + m] = ha_run[nt];
    }
  }
  __syncthreads();

  // ---- Phase B: block compose + tagged-atomic lookback (threads 0..31)
  if (tid < 32){
    float Pw[4], Hw[4];
#pragma unroll
    for (int w2 = 0; w2 < 4; ++w2){ Pw[w2] = sPw[w2][tid]; Hw[w2] = sHw[w2][tid]; }
    float Sj = 0.f;
    if (bx & 7){
      unsigned long long* src = Sbuf + (size_t)(by*16 + bx - 1)*32 + tid;
      unsigned long long v;
      for (;;){
        v = __hip_atomic_load(src, __ATOMIC_RELAXED, __HIP_MEMORY_SCOPE_AGENT);
        if ((unsigned)(v >> 32) == 1u) break;
        __builtin_amdgcn_s_sleep(2);
      }
      Sj = __uint_as_float((unsigned)v);
    }
    float s = Sj;
#pragma unroll
    for (int w2 = 0; w2 < 4; ++w2){
      sIw[w2][tid] = s;
      s = Pw[w2]*s + Hw[w2];
    }
    unsigned long long pv = (1ull << 32) | (unsigned long long)__float_as_uint(s);
    __hip_atomic_store(Sbuf + (size_t)(by*16 + bx)*32 + tid, pv,
                       __ATOMIC_RELAXED, __HIP_MEMORY_SCOPE_AGENT);
  }
  __syncthreads();

  // ---- Phase C: fixup + transpose + store
  float iw[2];
#pragma unroll
  for (int nt = 0; nt < 2; ++nt) iw[nt] = sIw[wv][nt*16 + m];
#pragma unroll
  for (int i = 0; i < 4; ++i){
    const int tile = bx*16 + wv*4 + i;
#pragma unroll
    for (int nt = 0; nt < 2; ++nt){
      float it = pe_t[i][nt]*iw[nt] + he_t[i][nt];
#pragma unroll
      for (int j = 0; j < 2; ++j){
        unsigned yp = ypk[i][nt][j], cp = cpk[i][nt][j];
        float y0 = __uint_as_float(yp << 16);
        float y1 = __uint_as_float(yp & 0xffff0000u);
        float c0 = __uint_as_float(cp << 16);
        float c1 = __uint_as_float(cp & 0xffff0000u);
        sYT[wv][(q*4 + j*2 + 0)*40 + nt*16 + m] = f2b(y0 + c0*it);
        sYT[wv][(q*4 + j*2 + 1)*40 + nt*16 + m] = f2b(y1 + c1*it);
      }
    }
    short8 yv = *(const short8*)&sYT[wv][m*40 + q*8];
    *(short8*)(ybp + (size_t)tile*32768 + (size_t)by*512 + (size_t)lane*8) = yv;
  }
}

// ---------------- 3. output projection (direct, no LDS reduce) ----------------
// grid NTILE=256, block 256. Wave wv handles d-tiles wv*2, wv*2+1 over full K.
__global__ void outproj_kernel(const unsigned short* __restrict__ ybp,
                               const unsigned short* __restrict__ Wop,
                               const float* __restrict__ b_out,
                               float* __restrict__ out){
  const int tid  = threadIdx.x;
  const int lane = tid & 63;
  const int wv   = tid >> 6;
  const int m    = lane & 15;
  const int q    = lane >> 4;
  const int tile = blockIdx.x;
  const int dt0  = wv*2;

  floatx4 acc0 = {0.f,0.f,0.f,0.f}, acc1 = acc0;
  const unsigned short* aP = ybp + (size_t)tile*32768 + lane*8;
  const unsigned short* bP = Wop + (size_t)dt0*32768 + lane*8;
#pragma unroll 8
  for (int kk = 0; kk < 64; ++kk){
    short8 af = *(const short8*)(aP + (size_t)kk*512);
    short8 b0 = *(const short8*)(bP + (size_t)kk*512);
    short8 b1 = *(const short8*)(bP + 32768 + (size_t)kk*512);
    acc0 = __builtin_amdgcn_mfma_f32_16x16x32_bf16(af, b0, acc0, 0, 0, 0);
    acc1 = __builtin_amdgcn_mfma_f32_16x16x32_bf16(af, b1, acc1, 0, 0, 0);
  }
  const int d0 = dt0*16 + m;
  const float bo0 = b_out[d0], bo1 = b_out[d0 + 16];
#pragma unroll
  for (int r = 0; r < 4; ++r){
    const size_t row = (size_t)(tile*16 + q*4 + r)*DDIM;
    out[row + d0]      = acc0[r] + bo0;
    out[row + d0 + 16] = acc1[r] + bo1;
  }
}

extern "C" void kernel_launch(void* const* d_in, const int* in_sizes, int n_in,
                              void* d_out, int out_size, void* d_ws, size_t ws_size,
                              hipStream_t stream) {
  const float* x     = (const float*)d_in[0];
  const float* W_B   = (const float*)d_in[1];
  const float* b_B   = (const float*)d_in[2];
  const float* W_C   = (const float*)d_in[3];
  const float* b_C   = (const float*)d_in[4];
  const float* W_dt  = (const float*)d_in[5];
  const float* b_dt  = (const float*)d_in[6];
  const float* A_log = (const float*)d_in[7];
  const float* W_out = (const float*)d_in[8];
  const float* b_out = (const float*)d_in[9];
  float* out = (float*)d_out;

  char* w = (char*)d_ws;
  unsigned short* xp    = (unsigned short*)(w + 0x0000000);  // 1 MB
  unsigned short* Wp3   = (unsigned short*)(w + 0x0100000);  // 1.5 MB
  unsigned short* Wop   = (unsigned short*)(w + 0x0280000);  // 0.5 MB
  float*          Aval  = (float*)         (w + 0x0300000);  // 8 KB
  unsigned short* ybp   = (unsigned short*)(w + 0x0310000);  // 16 MB
  unsigned long long* Sbuf = (unsigned long long*)(w + 0x1310000); // 256 KB
  // total ~19.4 MB

  prep_kernel<<<384, 256, 0, stream>>>(
      x, W_B, W_C, W_dt, A_log, W_out, xp, Wp3, Wop, Aval, Sbuf);

  projscan_kernel<<<dim3(16, 64), 256, 0, stream>>>(
      xp, Wp3, b_B, b_dt, b_C, Aval, Sbuf, ybp);

  outproj_kernel<<<NTILE, 256, 0, stream>>>(ybp, Wop, b_out, out);
}